// Round 7
// baseline (302.934 us; speedup 1.0000x reference)
//
#include <hip/hip_runtime.h>
#include <hip/hip_bf16.h>

#define D 128

typedef __bf16 bf16x8 __attribute__((ext_vector_type(8)));
typedef float f32x4 __attribute__((ext_vector_type(4)));

// stored col j  <->  true col PI(j) = (j&7)*16 + (j>>3);  PI_inv(c) = (c&15)*8 + (c>>4)

// ---------------- prep: pack weights + zero counts + init scan control ----------------
// blocks [0,128): pack W1/W2 into bf16 MFMA B-fragment order.
// blocks [128, 128+zb): zero counts.  last block: init ticket + flags.
// Fragment slot (k_slot, n): lane quad*16+nl holds B[kchunk*32+quad*8+j][ntile*16+nl],
// packed at o = ((ntile*4+kchunk)*64 + quad*16 + nl)*8 + j.
// Layer 1: k_slot = k. Layer 2: k_slot = PI_inv(k) (A = h stored in PI-permuted cols).

__global__ void prep_kernel(const float* __restrict__ W1, const float* __restrict__ W2,
                            __bf16* __restrict__ pw, int* __restrict__ counts,
                            int* __restrict__ ctrl, int n, int nzb) {
    int b = blockIdx.x;
    if (b < 128) {
        int t = b * 256 + threadIdx.x;  // 0..32767
        int which = t >> 14, idx = t & 16383;
        const float* W = which ? W2 : W1;
        float w = W[idx];
        int k = idx >> 7, nn = idx & 127;
        int ks = which ? (((k & 15) << 3) | (k >> 4)) : k;  // PI_inv for layer 2
        int ntile = nn >> 4, nl = nn & 15;
        int kchunk = ks >> 5, quad = (ks >> 3) & 3, j = ks & 7;
        int o = (((ntile * 4 + kchunk) * 64 + quad * 16 + nl) << 3) + j;
        pw[(size_t)which * 16384 + o] = (__bf16)w;
    } else if (b < 128 + nzb) {
        int i0 = (b - 128) * 1024 + threadIdx.x * 4;
        if (i0 + 4 <= n) {
            *(int4*)(counts + i0) = make_int4(0, 0, 0, 0);
        } else {
            for (int i = i0; i < n; i++) counts[i] = 0;
        }
    } else {
        int t = threadIdx.x;
        if (t == 0) ctrl[0] = 0;                    // ticket
        if (t < 64) ctrl[1 + t] = -1;               // flags sentinel
    }
}

// ---------------- count: in-degree + per-edge slot (8x MLP) ----------------

__global__ void count_kernel(const int* __restrict__ dst, int* __restrict__ counts,
                             int* __restrict__ eoff, int e) {
    int i0 = (blockIdx.x * 256 + threadIdx.x) * 8;
    if (i0 + 8 <= e) {
        int4 a = *(const int4*)(dst + i0);
        int4 b = *(const int4*)(dst + i0 + 4);
        int4 oa, ob;
        oa.x = atomicAdd(&counts[a.x], 1);
        oa.y = atomicAdd(&counts[a.y], 1);
        oa.z = atomicAdd(&counts[a.z], 1);
        oa.w = atomicAdd(&counts[a.w], 1);
        ob.x = atomicAdd(&counts[b.x], 1);
        ob.y = atomicAdd(&counts[b.y], 1);
        ob.z = atomicAdd(&counts[b.z], 1);
        ob.w = atomicAdd(&counts[b.w], 1);
        *(int4*)(eoff + i0) = oa;
        *(int4*)(eoff + i0 + 4) = ob;
    } else {
        for (int i = i0; i < e; i++) eoff[i] = atomicAdd(&counts[dst[i]], 1);
    }
}

// ------- fused scan: dinv + exclusive row_ptr via ticket-ordered chained prefix -------
// ctrl[0]=ticket, ctrl[1..]=flags (running inclusive chunk prefix, -1 = not ready).
// Deadlock-free: ticket i implies all tickets < i already started.

__global__ void scan_fused(const int* __restrict__ counts, float* __restrict__ dinv,
                           int* __restrict__ row_ptr, int* __restrict__ ctrl, int n) {
    __shared__ int sm[256];
    __shared__ int schunk, sbase;
    int t = threadIdx.x;
    if (t == 0) schunk = atomicAdd(&ctrl[0], 1);
    __syncthreads();
    int chunk = schunk;
    int base = chunk * 2048 + t * 8;
    int c[8], local[8];
    int s = 0;
#pragma unroll
    for (int j = 0; j < 8; j++) {
        int idx = base + j;
        c[j] = (idx < n) ? counts[idx] : 0;
        local[j] = s; s += c[j];
        if (idx < n) dinv[idx] = rsqrtf((float)(c[j] + 1));  // +1 self loop
    }
    sm[t] = s; __syncthreads();
    int own = s;
    for (int off = 1; off < 256; off <<= 1) {
        int u = (t >= off) ? sm[t - off] : 0;
        __syncthreads();
        sm[t] += u;
        __syncthreads();
    }
    if (t == 0) {
        int prev = 0;
        if (chunk > 0) {
            while ((prev = __hip_atomic_load(&ctrl[1 + chunk - 1], __ATOMIC_ACQUIRE,
                                             __HIP_MEMORY_SCOPE_AGENT)) < 0) {}
        }
        sbase = prev;
        __hip_atomic_store(&ctrl[1 + chunk], prev + sm[255], __ATOMIC_RELEASE,
                           __HIP_MEMORY_SCOPE_AGENT);
    }
    __syncthreads();
    int basev = sbase + sm[t] - own;
#pragma unroll
    for (int j = 0; j < 8; j++) { int idx = base + j; if (idx < n) row_ptr[idx] = basev + local[j]; }
}

// ------- fill: no atomics (slot from eoff); entry packs {src, norm}; 8x MLP -------

__global__ void fill_kernel(const int* __restrict__ src, const int* __restrict__ dst,
                            const int* __restrict__ row_ptr, const int* __restrict__ eoff,
                            const float* __restrict__ dinv, int2* __restrict__ csr, int e) {
    int i0 = (blockIdx.x * 256 + threadIdx.x) * 8;
    if (i0 + 8 <= e) {
        int4 sa = *(const int4*)(src + i0);
        int4 sb = *(const int4*)(src + i0 + 4);
        int4 da = *(const int4*)(dst + i0);
        int4 db = *(const int4*)(dst + i0 + 4);
        int4 oa = *(const int4*)(eoff + i0);
        int4 ob = *(const int4*)(eoff + i0 + 4);
        int sv[8] = {sa.x, sa.y, sa.z, sa.w, sb.x, sb.y, sb.z, sb.w};
        int dv[8] = {da.x, da.y, da.z, da.w, db.x, db.y, db.z, db.w};
        int ov[8] = {oa.x, oa.y, oa.z, oa.w, ob.x, ob.y, ob.z, ob.w};
        int p[8]; float ww[8];
#pragma unroll
        for (int u = 0; u < 8; u++) p[u] = row_ptr[dv[u]] + ov[u];
#pragma unroll
        for (int u = 0; u < 8; u++) ww[u] = dinv[sv[u]] * dinv[dv[u]];
#pragma unroll
        for (int u = 0; u < 8; u++) csr[p[u]] = make_int2(sv[u], __float_as_int(ww[u]));
    } else {
        for (int i = i0; i < e; i++) {
            int s = src[i], d = dst[i];
            int pos = row_ptr[d] + eoff[i];
            csr[pos] = make_int2(s, __float_as_int(dinv[s] * dinv[d]));
        }
    }
}

// ---------------- GEMM1: Zs = X(fp32) @ W1bf16, A split 2-term, B in LDS ----------------
// 4 waves/block, 16 rows/wave, 64 rows/block. Output bf16, PI-permuted cols.

__global__ void gemm1_mfma(const float* __restrict__ X, const __bf16* __restrict__ PW,
                           __bf16* __restrict__ Zs, int nrows) {
    __shared__ bf16x8 sB[2048];  // 32 KB packed W
    int t = threadIdx.x;
    const bf16x8* PW8 = (const bf16x8*)PW;
#pragma unroll
    for (int i = 0; i < 8; i++) sB[t + 256 * i] = PW8[t + 256 * i];

    int wave = t >> 6, lane = t & 63;
    int qm = lane & 15, quad = lane >> 4;
    int r0 = blockIdx.x * 64 + wave * 16;
    int row = r0 + qm;
    bool valid = row < nrows;
    const float* xr = X + (size_t)row * D + quad * 8;

    bf16x8 ahi[4], alo[4];
#pragma unroll
    for (int c = 0; c < 4; c++) {
        float4 zf = {0.f, 0.f, 0.f, 0.f};
        float4 xa = valid ? ((const float4*)(xr + c * 32))[0] : zf;
        float4 xb = valid ? ((const float4*)(xr + c * 32))[1] : zf;
        float xs[8] = {xa.x, xa.y, xa.z, xa.w, xb.x, xb.y, xb.z, xb.w};
        bf16x8 h, l;
#pragma unroll
        for (int j = 0; j < 8; j++) {
            float v = xs[j];
            __bf16 hh = (__bf16)v;
            h[j] = hh;
            l[j] = (__bf16)(v - (float)hh);
        }
        ahi[c] = h; alo[c] = l;
    }

    f32x4 acc[8];
#pragma unroll
    for (int nt = 0; nt < 8; nt++) acc[nt] = (f32x4){0.f, 0.f, 0.f, 0.f};

    __syncthreads();

#pragma unroll
    for (int c = 0; c < 4; c++) {
#pragma unroll
        for (int nt = 0; nt < 8; nt++) {
            bf16x8 b = sB[(nt * 4 + c) * 64 + lane];
            acc[nt] = __builtin_amdgcn_mfma_f32_16x16x32_bf16(ahi[c], b, acc[nt], 0, 0, 0);
            acc[nt] = __builtin_amdgcn_mfma_f32_16x16x32_bf16(alo[c], b, acc[nt], 0, 0, 0);
        }
    }

    // C/D: true col = nt*16+qm -> stored col qm*8+nt (contiguous); row = quad*4+reg
#pragma unroll
    for (int reg = 0; reg < 4; reg++) {
        int orow = r0 + quad * 4 + reg;
        if (orow < nrows) {
            bf16x8 o;
#pragma unroll
            for (int nt = 0; nt < 8; nt++) o[nt] = (__bf16)acc[nt][reg];
            *(bf16x8*)(Zs + (size_t)orow * D + qm * 8) = o;
        }
    }
}

// ---------------- GEMM2: Zs2 = Hs(bf16, PI cols) @ W2bf16, 1-term, B in LDS ----------------

__global__ void gemm2_mfma(const __bf16* __restrict__ Hs, const __bf16* __restrict__ PW,
                           __bf16* __restrict__ Zs, int nrows) {
    __shared__ bf16x8 sB[2048];  // 32 KB
    int t = threadIdx.x;
    const bf16x8* PW8 = (const bf16x8*)PW;
#pragma unroll
    for (int i = 0; i < 8; i++) sB[t + 256 * i] = PW8[t + 256 * i];

    int wave = t >> 6, lane = t & 63;
    int qm = lane & 15, quad = lane >> 4;
    int r0 = blockIdx.x * 64 + wave * 16;
    int row = r0 + qm;
    bool valid = row < nrows;
    const __bf16* hr = Hs + (size_t)row * D + quad * 8;

    bf16x8 a[4];
#pragma unroll
    for (int c = 0; c < 4; c++) {
        bf16x8 z8 = {};
        a[c] = valid ? *(const bf16x8*)(hr + c * 32) : z8;
    }

    f32x4 acc[8];
#pragma unroll
    for (int nt = 0; nt < 8; nt++) acc[nt] = (f32x4){0.f, 0.f, 0.f, 0.f};

    __syncthreads();

#pragma unroll
    for (int c = 0; c < 4; c++) {
#pragma unroll
        for (int nt = 0; nt < 8; nt++) {
            bf16x8 b = sB[(nt * 4 + c) * 64 + lane];
            acc[nt] = __builtin_amdgcn_mfma_f32_16x16x32_bf16(a[c], b, acc[nt], 0, 0, 0);
        }
    }

#pragma unroll
    for (int reg = 0; reg < 4; reg++) {
        int orow = r0 + quad * 4 + reg;
        if (orow < nrows) {
            bf16x8 o;
#pragma unroll
            for (int nt = 0; nt < 8; nt++) o[nt] = (__bf16)acc[nt][reg];
            *(bf16x8*)(Zs + (size_t)orow * D + qm * 8) = o;
        }
    }
}

// ------- agg1: Hs[v] = relu(dinv^2*Zs[v] + sum w*Zs[s] + b1) -------
// 16 lanes/node, bf16x8 (16B) gathers, 8x/4x/1x edge unroll; csr entry = {src, norm}.

__global__ void agg1_kernel(const __bf16* __restrict__ Zs, const int* __restrict__ row_ptr,
                            const int* __restrict__ counts, const int2* __restrict__ csr,
                            const float* __restrict__ dinv, const float* __restrict__ bias,
                            __bf16* __restrict__ Hs, int n) {
    int t = blockIdx.x * 256 + threadIdx.x;
    int v = t >> 4, c = t & 15;
    if (v >= n) return;
    float dv = dinv[v];
    const bf16x8* Z8 = (const bf16x8*)Zs;  // row stride 16 chunks
    bf16x8 zc = Z8[(size_t)v * 16 + c];
    float sw = dv * dv;
    float acc[8];
#pragma unroll
    for (int j = 0; j < 8; j++) acc[j] = (float)zc[j] * sw;
    int start = row_ptr[v], cnt = counts[v];
    int i = 0;
    for (; i + 8 <= cnt; i += 8) {
        int2 ee[8]; bf16x8 mm[8];
#pragma unroll
        for (int u = 0; u < 8; u++) ee[u] = csr[start + i + u];
#pragma unroll
        for (int u = 0; u < 8; u++) mm[u] = Z8[(size_t)ee[u].x * 16 + c];
#pragma unroll
        for (int u = 0; u < 8; u++) {
            float w = __int_as_float(ee[u].y);
#pragma unroll
            for (int j = 0; j < 8; j++) acc[j] = fmaf(w, (float)mm[u][j], acc[j]);
        }
    }
    for (; i + 4 <= cnt; i += 4) {
        int2 e0 = csr[start + i], e1 = csr[start + i + 1];
        int2 e2 = csr[start + i + 2], e3 = csr[start + i + 3];
        bf16x8 m0 = Z8[(size_t)e0.x * 16 + c];
        bf16x8 m1 = Z8[(size_t)e1.x * 16 + c];
        bf16x8 m2 = Z8[(size_t)e2.x * 16 + c];
        bf16x8 m3 = Z8[(size_t)e3.x * 16 + c];
        float w0 = __int_as_float(e0.y), w1 = __int_as_float(e1.y);
        float w2 = __int_as_float(e2.y), w3 = __int_as_float(e3.y);
#pragma unroll
        for (int j = 0; j < 8; j++) acc[j] = fmaf(w0, (float)m0[j], acc[j]);
#pragma unroll
        for (int j = 0; j < 8; j++) acc[j] = fmaf(w1, (float)m1[j], acc[j]);
#pragma unroll
        for (int j = 0; j < 8; j++) acc[j] = fmaf(w2, (float)m2[j], acc[j]);
#pragma unroll
        for (int j = 0; j < 8; j++) acc[j] = fmaf(w3, (float)m3[j], acc[j]);
    }
    for (; i < cnt; i++) {
        int2 e0 = csr[start + i];
        float w0 = __int_as_float(e0.y);
        bf16x8 m0 = Z8[(size_t)e0.x * 16 + c];
#pragma unroll
        for (int j = 0; j < 8; j++) acc[j] = fmaf(w0, (float)m0[j], acc[j]);
    }
    bf16x8 o;
#pragma unroll
    for (int j = 0; j < 8; j++) o[j] = (__bf16)fmaxf(acc[j] + bias[j * 16 + c], 0.f);
    ((bf16x8*)Hs)[(size_t)v * 16 + c] = o;
}

// ------- agg2 + fc fused: out[v,2] = relu(agg(Zs2) + b2) @ Wfc + bfc -------

__global__ void agg2_fc_kernel(const __bf16* __restrict__ Zs, const int* __restrict__ row_ptr,
                               const int* __restrict__ counts, const int2* __restrict__ csr,
                               const float* __restrict__ dinv, const float* __restrict__ bias,
                               const float* __restrict__ Wfc, const float* __restrict__ bfc,
                               float* __restrict__ out, int n) {
    int t = blockIdx.x * 256 + threadIdx.x;
    int v = t >> 4, c = t & 15;
    if (v >= n) return;
    float dv = dinv[v];
    const bf16x8* Z8 = (const bf16x8*)Zs;
    bf16x8 zc = Z8[(size_t)v * 16 + c];
    float sw = dv * dv;
    float acc[8];
#pragma unroll
    for (int j = 0; j < 8; j++) acc[j] = (float)zc[j] * sw;
    int start = row_ptr[v], cnt = counts[v];
    int i = 0;
    for (; i + 8 <= cnt; i += 8) {
        int2 ee[8]; bf16x8 mm[8];
#pragma unroll
        for (int u = 0; u < 8; u++) ee[u] = csr[start + i + u];
#pragma unroll
        for (int u = 0; u < 8; u++) mm[u] = Z8[(size_t)ee[u].x * 16 + c];
#pragma unroll
        for (int u = 0; u < 8; u++) {
            float w = __int_as_float(ee[u].y);
#pragma unroll
            for (int j = 0; j < 8; j++) acc[j] = fmaf(w, (float)mm[u][j], acc[j]);
        }
    }
    for (; i + 4 <= cnt; i += 4) {
        int2 e0 = csr[start + i], e1 = csr[start + i + 1];
        int2 e2 = csr[start + i + 2], e3 = csr[start + i + 3];
        bf16x8 m0 = Z8[(size_t)e0.x * 16 + c];
        bf16x8 m1 = Z8[(size_t)e1.x * 16 + c];
        bf16x8 m2 = Z8[(size_t)e2.x * 16 + c];
        bf16x8 m3 = Z8[(size_t)e3.x * 16 + c];
        float w0 = __int_as_float(e0.y), w1 = __int_as_float(e1.y);
        float w2 = __int_as_float(e2.y), w3 = __int_as_float(e3.y);
#pragma unroll
        for (int j = 0; j < 8; j++) acc[j] = fmaf(w0, (float)m0[j], acc[j]);
#pragma unroll
        for (int j = 0; j < 8; j++) acc[j] = fmaf(w1, (float)m1[j], acc[j]);
#pragma unroll
        for (int j = 0; j < 8; j++) acc[j] = fmaf(w2, (float)m2[j], acc[j]);
#pragma unroll
        for (int j = 0; j < 8; j++) acc[j] = fmaf(w3, (float)m3[j], acc[j]);
    }
    for (; i < cnt; i++) {
        int2 e0 = csr[start + i];
        float w0 = __int_as_float(e0.y);
        bf16x8 m0 = Z8[(size_t)e0.x * 16 + c];
#pragma unroll
        for (int j = 0; j < 8; j++) acc[j] = fmaf(w0, (float)m0[j], acc[j]);
    }
    float a0 = 0.f, a1 = 0.f;
#pragma unroll
    for (int j = 0; j < 8; j++) {
        int p = j * 16 + c;  // true col
        float hj = fmaxf(acc[j] + bias[p], 0.f);
        a0 = fmaf(hj, Wfc[p * 2], a0);
        a1 = fmaf(hj, Wfc[p * 2 + 1], a1);
    }
#pragma unroll
    for (int off = 8; off > 0; off >>= 1) {
        a0 += __shfl_down(a0, off, 16);
        a1 += __shfl_down(a1, off, 16);
    }
    if (c == 0) {
        out[(size_t)v * 2 + 0] = a0 + bfc[0];
        out[(size_t)v * 2 + 1] = a1 + bfc[1];
    }
}

// ---------------- launch ----------------

extern "C" void kernel_launch(void* const* d_in, const int* in_sizes, int n_in,
                              void* d_out, int out_size, void* d_ws, size_t ws_size,
                              hipStream_t stream) {
    const float* x   = (const float*)d_in[0];
    const int*   ei  = (const int*)d_in[1];
    const float* W1  = (const float*)d_in[2];
    const float* b1  = (const float*)d_in[3];
    const float* W2  = (const float*)d_in[4];
    const float* b2  = (const float*)d_in[5];
    const float* Wfc = (const float*)d_in[6];
    const float* bfc = (const float*)d_in[7];
    float* out = (float*)d_out;

    int n = in_sizes[0] / D;   // 100000
    int e = in_sizes[1] / 2;   // 640000
    const int* src = ei;
    const int* dst = ei + e;

    // workspace layout (16B-aligned at these sizes)
    char* ws = (char*)d_ws;
    size_t nb = (size_t)n * 4;
    int*    counts  = (int*)(ws);
    float*  dinv    = (float*)(ws + nb);
    int*    rowptr  = (int*)(ws + 2 * nb);
    int*    ctrl    = (int*)(ws + 3 * nb);                     // 1024 B: ticket + flags
    int*    eoff    = (int*)(ws + 3 * nb + 1024);
    int2*   csr     = (int2*)(ws + 3 * nb + 1024 + (size_t)e * 4);
    __bf16* pw      = (__bf16*)(ws + 3 * nb + 1024 + (size_t)e * 12);  // 64 KB packed (W1|W2)
    __bf16* z1      = (__bf16*)(ws + 3 * nb + 1024 + (size_t)e * 12 + 65536);
    __bf16* h1      = z1 + (size_t)n * D;
    __bf16* z2      = h1 + (size_t)n * D;

    int nzb = (n + 1023) / 1024;               // counts-zero blocks
    int e8b = ((e + 7) / 8 + 255) / 256;       // 8x edge-parallel blocks
    int scb = (n + 2047) / 2048;               // scan chunks (<= 64)
    int gb  = (n + 63) / 64;
    int ab  = ((n * 16) + 255) / 256;

    prep_kernel<<<128 + nzb + 1, 256, 0, stream>>>(W1, W2, pw, counts, ctrl, n, nzb);
    count_kernel<<<e8b, 256, 0, stream>>>(dst, counts, eoff, e);
    scan_fused<<<scb, 256, 0, stream>>>(counts, dinv, rowptr, ctrl, n);
    fill_kernel<<<e8b, 256, 0, stream>>>(src, dst, rowptr, eoff, dinv, csr, e);

    // layer 1
    gemm1_mfma<<<gb, 256, 0, stream>>>(x, pw, z1, n);
    agg1_kernel<<<ab, 256, 0, stream>>>(z1, rowptr, counts, csr, dinv, b1, h1, n);
    // layer 2
    gemm2_mfma<<<gb, 256, 0, stream>>>(h1, pw + 16384, z2, n);
    agg2_fc_kernel<<<ab, 256, 0, stream>>>(z2, rowptr, counts, csr, dinv, b2, Wfc, bfc, out, n);
}

// Round 8
// 240.572 us; speedup vs baseline: 1.2592x; 1.2592x over previous
//
#include <hip/hip_runtime.h>
#include <hip/hip_bf16.h>

#define D 128

typedef __bf16 bf16x8 __attribute__((ext_vector_type(8)));
typedef float f32x4 __attribute__((ext_vector_type(4)));

// stored col j  <->  true col PI(j) = (j&7)*16 + (j>>3);  PI_inv(c) = (c&15)*8 + (c>>4)

// ---------------- prep: pack weights + zero counts ----------------
// blocks [0,128): pack W1/W2 into bf16 MFMA B-fragment order.
// blocks [128, 128+nzb): zero counts.
// Fragment slot (k_slot, n): lane quad*16+nl holds B[kchunk*32+quad*8+j][ntile*16+nl],
// packed at o = ((ntile*4+kchunk)*64 + quad*16 + nl)*8 + j.
// Layer 1: k_slot = k. Layer 2: k_slot = PI_inv(k) (A = h stored in PI-permuted cols).

__global__ void prep_kernel(const float* __restrict__ W1, const float* __restrict__ W2,
                            __bf16* __restrict__ pw, int* __restrict__ counts, int n) {
    int b = blockIdx.x;
    if (b < 128) {
        int t = b * 256 + threadIdx.x;  // 0..32767
        int which = t >> 14, idx = t & 16383;
        const float* W = which ? W2 : W1;
        float w = W[idx];
        int k = idx >> 7, nn = idx & 127;
        int ks = which ? (((k & 15) << 3) | (k >> 4)) : k;  // PI_inv for layer 2
        int ntile = nn >> 4, nl = nn & 15;
        int kchunk = ks >> 5, quad = (ks >> 3) & 3, j = ks & 7;
        int o = (((ntile * 4 + kchunk) * 64 + quad * 16 + nl) << 3) + j;
        pw[(size_t)which * 16384 + o] = (__bf16)w;
    } else {
        int i0 = (b - 128) * 1024 + threadIdx.x * 4;
        if (i0 + 4 <= n) {
            *(int4*)(counts + i0) = make_int4(0, 0, 0, 0);
        } else {
            for (int i = i0; i < n; i++) counts[i] = 0;
        }
    }
}

// ------- mega1: gemm1 (blocks [0,gb)) co-scheduled with count (blocks [gb, gb+e4b)) -------
// gemm1: Zs = X(fp32) @ W1bf16, A split 2-term, B staged in LDS.
//   4 waves/block, 16 rows/wave, 64 rows/block. Output bf16, PI-permuted cols.
// count: in-degree atomics + per-edge slot capture (4x MLP). Independent of gemm1.

__global__ void mega1_kernel(const float* __restrict__ X, const __bf16* __restrict__ PW,
                             __bf16* __restrict__ Zs, int nrows, int gb,
                             const int* __restrict__ dst, int* __restrict__ counts,
                             int* __restrict__ eoff, int e) {
    __shared__ bf16x8 sB[2048];  // 32 KB packed W (gemm path only)
    int b = blockIdx.x;
    if (b >= gb) {
        // ---- count path ----
        int i0 = ((b - gb) * 256 + threadIdx.x) * 4;
        if (i0 + 4 <= e) {
            int4 d4 = *(const int4*)(dst + i0);
            int4 o;
            o.x = atomicAdd(&counts[d4.x], 1);
            o.y = atomicAdd(&counts[d4.y], 1);
            o.z = atomicAdd(&counts[d4.z], 1);
            o.w = atomicAdd(&counts[d4.w], 1);
            *(int4*)(eoff + i0) = o;
        } else {
            for (int i = i0; i < e; i++) eoff[i] = atomicAdd(&counts[dst[i]], 1);
        }
        return;
    }
    // ---- gemm1 path ----
    int t = threadIdx.x;
    const bf16x8* PW8 = (const bf16x8*)PW;
#pragma unroll
    for (int i = 0; i < 8; i++) sB[t + 256 * i] = PW8[t + 256 * i];

    int wave = t >> 6, lane = t & 63;
    int qm = lane & 15, quad = lane >> 4;
    int r0 = b * 64 + wave * 16;
    int row = r0 + qm;
    bool valid = row < nrows;
    const float* xr = X + (size_t)row * D + quad * 8;

    bf16x8 ahi[4], alo[4];
#pragma unroll
    for (int c = 0; c < 4; c++) {
        float4 zf = {0.f, 0.f, 0.f, 0.f};
        float4 xa = valid ? ((const float4*)(xr + c * 32))[0] : zf;
        float4 xb = valid ? ((const float4*)(xr + c * 32))[1] : zf;
        float xs[8] = {xa.x, xa.y, xa.z, xa.w, xb.x, xb.y, xb.z, xb.w};
        bf16x8 h, l;
#pragma unroll
        for (int j = 0; j < 8; j++) {
            float v = xs[j];
            __bf16 hh = (__bf16)v;
            h[j] = hh;
            l[j] = (__bf16)(v - (float)hh);
        }
        ahi[c] = h; alo[c] = l;
    }

    f32x4 acc[8];
#pragma unroll
    for (int nt = 0; nt < 8; nt++) acc[nt] = (f32x4){0.f, 0.f, 0.f, 0.f};

    __syncthreads();

#pragma unroll
    for (int c = 0; c < 4; c++) {
#pragma unroll
        for (int nt = 0; nt < 8; nt++) {
            bf16x8 bb = sB[(nt * 4 + c) * 64 + lane];
            acc[nt] = __builtin_amdgcn_mfma_f32_16x16x32_bf16(ahi[c], bb, acc[nt], 0, 0, 0);
            acc[nt] = __builtin_amdgcn_mfma_f32_16x16x32_bf16(alo[c], bb, acc[nt], 0, 0, 0);
        }
    }

    // C/D: true col = nt*16+qm -> stored col qm*8+nt (contiguous); row = quad*4+reg
#pragma unroll
    for (int reg = 0; reg < 4; reg++) {
        int orow = r0 + quad * 4 + reg;
        if (orow < nrows) {
            bf16x8 o;
#pragma unroll
            for (int nt = 0; nt < 8; nt++) o[nt] = (__bf16)acc[nt][reg];
            *(bf16x8*)(Zs + (size_t)orow * D + qm * 8) = o;
        }
    }
}

// ---------------- 3-kernel tree scan of counts -> row_ptr (+ dinv in down phase) ---------

__global__ void scan_part(const int* __restrict__ counts, int* __restrict__ partial, int n) {
    __shared__ int sm[256];
    int b = blockIdx.x, t = threadIdx.x;
    int base = b * 2048 + t * 8;
    int s = 0;
#pragma unroll
    for (int j = 0; j < 8; j++) { int idx = base + j; if (idx < n) s += counts[idx]; }
    sm[t] = s; __syncthreads();
    for (int off = 128; off > 0; off >>= 1) { if (t < off) sm[t] += sm[t + off]; __syncthreads(); }
    if (t == 0) partial[b] = sm[0];
}

__global__ void scan_top(int* partial, int nb) {
    __shared__ int sm[256];
    int t = threadIdx.x;
    int v = (t < nb) ? partial[t] : 0;
    sm[t] = v; __syncthreads();
    for (int off = 1; off < 256; off <<= 1) {
        int u = (t >= off) ? sm[t - off] : 0;
        __syncthreads();
        sm[t] += u;
        __syncthreads();
    }
    if (t < nb) partial[t] = sm[t] - v;  // exclusive
}

__global__ void scan_down(const int* __restrict__ counts, const int* __restrict__ blockoff,
                          int* __restrict__ row_ptr, float* __restrict__ dinv, int n) {
    __shared__ int sm[256];
    int b = blockIdx.x, t = threadIdx.x;
    int base = b * 2048 + t * 8;
    int c[8], local[8];
    int s = 0;
#pragma unroll
    for (int j = 0; j < 8; j++) {
        int idx = base + j;
        c[j] = (idx < n) ? counts[idx] : 0;
        local[j] = s; s += c[j];
        if (idx < n) dinv[idx] = rsqrtf((float)(c[j] + 1));  // +1 self loop
    }
    sm[t] = s; __syncthreads();
    int own = s;
    for (int off = 1; off < 256; off <<= 1) {
        int u = (t >= off) ? sm[t - off] : 0;
        __syncthreads();
        sm[t] += u;
        __syncthreads();
    }
    int basev = blockoff[b] + sm[t] - own;
#pragma unroll
    for (int j = 0; j < 8; j++) { int idx = base + j; if (idx < n) row_ptr[idx] = basev + local[j]; }
}

// ------- fill: no atomics (slot from eoff); entry packs {src, norm}; 4x MLP -------

__global__ void fill_kernel(const int* __restrict__ src, const int* __restrict__ dst,
                            const int* __restrict__ row_ptr, const int* __restrict__ eoff,
                            const float* __restrict__ dinv, int2* __restrict__ csr, int e) {
    int i0 = (blockIdx.x * 256 + threadIdx.x) * 4;
    if (i0 + 4 <= e) {
        int4 s4 = *(const int4*)(src + i0);
        int4 d4 = *(const int4*)(dst + i0);
        int4 o4 = *(const int4*)(eoff + i0);
        int p0 = row_ptr[d4.x] + o4.x;
        int p1 = row_ptr[d4.y] + o4.y;
        int p2 = row_ptr[d4.z] + o4.z;
        int p3 = row_ptr[d4.w] + o4.w;
        float w0 = dinv[s4.x] * dinv[d4.x];
        float w1 = dinv[s4.y] * dinv[d4.y];
        float w2 = dinv[s4.z] * dinv[d4.z];
        float w3 = dinv[s4.w] * dinv[d4.w];
        csr[p0] = make_int2(s4.x, __float_as_int(w0));
        csr[p1] = make_int2(s4.y, __float_as_int(w1));
        csr[p2] = make_int2(s4.z, __float_as_int(w2));
        csr[p3] = make_int2(s4.w, __float_as_int(w3));
    } else {
        for (int i = i0; i < e; i++) {
            int s = src[i], d = dst[i];
            int pos = row_ptr[d] + eoff[i];
            csr[pos] = make_int2(s, __float_as_int(dinv[s] * dinv[d]));
        }
    }
}

// ---------------- GEMM2: Zs2 = Hs(bf16, PI cols) @ W2bf16, 1-term, B in LDS ----------------

__global__ void gemm2_mfma(const __bf16* __restrict__ Hs, const __bf16* __restrict__ PW,
                           __bf16* __restrict__ Zs, int nrows) {
    __shared__ bf16x8 sB[2048];  // 32 KB
    int t = threadIdx.x;
    const bf16x8* PW8 = (const bf16x8*)PW;
#pragma unroll
    for (int i = 0; i < 8; i++) sB[t + 256 * i] = PW8[t + 256 * i];

    int wave = t >> 6, lane = t & 63;
    int qm = lane & 15, quad = lane >> 4;
    int r0 = blockIdx.x * 64 + wave * 16;
    int row = r0 + qm;
    bool valid = row < nrows;
    const __bf16* hr = Hs + (size_t)row * D + quad * 8;

    bf16x8 a[4];
#pragma unroll
    for (int c = 0; c < 4; c++) {
        bf16x8 z8 = {};
        a[c] = valid ? *(const bf16x8*)(hr + c * 32) : z8;
    }

    f32x4 acc[8];
#pragma unroll
    for (int nt = 0; nt < 8; nt++) acc[nt] = (f32x4){0.f, 0.f, 0.f, 0.f};

    __syncthreads();

#pragma unroll
    for (int c = 0; c < 4; c++) {
#pragma unroll
        for (int nt = 0; nt < 8; nt++) {
            bf16x8 b = sB[(nt * 4 + c) * 64 + lane];
            acc[nt] = __builtin_amdgcn_mfma_f32_16x16x32_bf16(a[c], b, acc[nt], 0, 0, 0);
        }
    }

#pragma unroll
    for (int reg = 0; reg < 4; reg++) {
        int orow = r0 + quad * 4 + reg;
        if (orow < nrows) {
            bf16x8 o;
#pragma unroll
            for (int nt = 0; nt < 8; nt++) o[nt] = (__bf16)acc[nt][reg];
            *(bf16x8*)(Zs + (size_t)orow * D + qm * 8) = o;
        }
    }
}

// ------- agg1: Hs[v] = relu(dinv^2*Zs[v] + sum w*Zs[s] + b1) -------
// 16 lanes/node, bf16x8 (16B) gathers, 4x edge unroll; csr entry = {src, norm}.

__global__ void agg1_kernel(const __bf16* __restrict__ Zs, const int* __restrict__ row_ptr,
                            const int* __restrict__ counts, const int2* __restrict__ csr,
                            const float* __restrict__ dinv, const float* __restrict__ bias,
                            __bf16* __restrict__ Hs, int n) {
    int t = blockIdx.x * 256 + threadIdx.x;
    int v = t >> 4, c = t & 15;
    if (v >= n) return;
    float dv = dinv[v];
    const bf16x8* Z8 = (const bf16x8*)Zs;  // row stride 16 chunks
    bf16x8 zc = Z8[(size_t)v * 16 + c];
    float sw = dv * dv;
    float acc[8];
#pragma unroll
    for (int j = 0; j < 8; j++) acc[j] = (float)zc[j] * sw;
    int start = row_ptr[v], cnt = counts[v];
    int i = 0;
    for (; i + 4 <= cnt; i += 4) {
        int2 e0 = csr[start + i], e1 = csr[start + i + 1];
        int2 e2 = csr[start + i + 2], e3 = csr[start + i + 3];
        bf16x8 m0 = Z8[(size_t)e0.x * 16 + c];
        bf16x8 m1 = Z8[(size_t)e1.x * 16 + c];
        bf16x8 m2 = Z8[(size_t)e2.x * 16 + c];
        bf16x8 m3 = Z8[(size_t)e3.x * 16 + c];
        float w0 = __int_as_float(e0.y), w1 = __int_as_float(e1.y);
        float w2 = __int_as_float(e2.y), w3 = __int_as_float(e3.y);
#pragma unroll
        for (int j = 0; j < 8; j++) acc[j] = fmaf(w0, (float)m0[j], acc[j]);
#pragma unroll
        for (int j = 0; j < 8; j++) acc[j] = fmaf(w1, (float)m1[j], acc[j]);
#pragma unroll
        for (int j = 0; j < 8; j++) acc[j] = fmaf(w2, (float)m2[j], acc[j]);
#pragma unroll
        for (int j = 0; j < 8; j++) acc[j] = fmaf(w3, (float)m3[j], acc[j]);
    }
    for (; i < cnt; i++) {
        int2 e0 = csr[start + i];
        float w0 = __int_as_float(e0.y);
        bf16x8 m0 = Z8[(size_t)e0.x * 16 + c];
#pragma unroll
        for (int j = 0; j < 8; j++) acc[j] = fmaf(w0, (float)m0[j], acc[j]);
    }
    bf16x8 o;
#pragma unroll
    for (int j = 0; j < 8; j++) o[j] = (__bf16)fmaxf(acc[j] + bias[j * 16 + c], 0.f);
    ((bf16x8*)Hs)[(size_t)v * 16 + c] = o;
}

// ------- agg2 + fc fused: out[v,2] = relu(agg(Zs2) + b2) @ Wfc + bfc -------

__global__ void agg2_fc_kernel(const __bf16* __restrict__ Zs, const int* __restrict__ row_ptr,
                               const int* __restrict__ counts, const int2* __restrict__ csr,
                               const float* __restrict__ dinv, const float* __restrict__ bias,
                               const float* __restrict__ Wfc, const float* __restrict__ bfc,
                               float* __restrict__ out, int n) {
    int t = blockIdx.x * 256 + threadIdx.x;
    int v = t >> 4, c = t & 15;
    if (v >= n) return;
    float dv = dinv[v];
    const bf16x8* Z8 = (const bf16x8*)Zs;
    bf16x8 zc = Z8[(size_t)v * 16 + c];
    float sw = dv * dv;
    float acc[8];
#pragma unroll
    for (int j = 0; j < 8; j++) acc[j] = (float)zc[j] * sw;
    int start = row_ptr[v], cnt = counts[v];
    int i = 0;
    for (; i + 4 <= cnt; i += 4) {
        int2 e0 = csr[start + i], e1 = csr[start + i + 1];
        int2 e2 = csr[start + i + 2], e3 = csr[start + i + 3];
        bf16x8 m0 = Z8[(size_t)e0.x * 16 + c];
        bf16x8 m1 = Z8[(size_t)e1.x * 16 + c];
        bf16x8 m2 = Z8[(size_t)e2.x * 16 + c];
        bf16x8 m3 = Z8[(size_t)e3.x * 16 + c];
        float w0 = __int_as_float(e0.y), w1 = __int_as_float(e1.y);
        float w2 = __int_as_float(e2.y), w3 = __int_as_float(e3.y);
#pragma unroll
        for (int j = 0; j < 8; j++) acc[j] = fmaf(w0, (float)m0[j], acc[j]);
#pragma unroll
        for (int j = 0; j < 8; j++) acc[j] = fmaf(w1, (float)m1[j], acc[j]);
#pragma unroll
        for (int j = 0; j < 8; j++) acc[j] = fmaf(w2, (float)m2[j], acc[j]);
#pragma unroll
        for (int j = 0; j < 8; j++) acc[j] = fmaf(w3, (float)m3[j], acc[j]);
    }
    for (; i < cnt; i++) {
        int2 e0 = csr[start + i];
        float w0 = __int_as_float(e0.y);
        bf16x8 m0 = Z8[(size_t)e0.x * 16 + c];
#pragma unroll
        for (int j = 0; j < 8; j++) acc[j] = fmaf(w0, (float)m0[j], acc[j]);
    }
    float a0 = 0.f, a1 = 0.f;
#pragma unroll
    for (int j = 0; j < 8; j++) {
        int p = j * 16 + c;  // true col
        float hj = fmaxf(acc[j] + bias[p], 0.f);
        a0 = fmaf(hj, Wfc[p * 2], a0);
        a1 = fmaf(hj, Wfc[p * 2 + 1], a1);
    }
#pragma unroll
    for (int off = 8; off > 0; off >>= 1) {
        a0 += __shfl_down(a0, off, 16);
        a1 += __shfl_down(a1, off, 16);
    }
    if (c == 0) {
        out[(size_t)v * 2 + 0] = a0 + bfc[0];
        out[(size_t)v * 2 + 1] = a1 + bfc[1];
    }
}

// ---------------- launch ----------------

extern "C" void kernel_launch(void* const* d_in, const int* in_sizes, int n_in,
                              void* d_out, int out_size, void* d_ws, size_t ws_size,
                              hipStream_t stream) {
    const float* x   = (const float*)d_in[0];
    const int*   ei  = (const int*)d_in[1];
    const float* W1  = (const float*)d_in[2];
    const float* b1  = (const float*)d_in[3];
    const float* W2  = (const float*)d_in[4];
    const float* b2  = (const float*)d_in[5];
    const float* Wfc = (const float*)d_in[6];
    const float* bfc = (const float*)d_in[7];
    float* out = (float*)d_out;

    int n = in_sizes[0] / D;   // 100000
    int e = in_sizes[1] / 2;   // 640000
    const int* src = ei;
    const int* dst = ei + e;

    // workspace layout (16B-aligned at these sizes)
    char* ws = (char*)d_ws;
    size_t nb = (size_t)n * 4;
    int*    counts  = (int*)(ws);
    float*  dinv    = (float*)(ws + nb);
    int*    rowptr  = (int*)(ws + 2 * nb);
    int*    partial = (int*)(ws + 3 * nb);                     // 1024 B reserved
    int*    eoff    = (int*)(ws + 3 * nb + 1024);
    int2*   csr     = (int2*)(ws + 3 * nb + 1024 + (size_t)e * 4);
    __bf16* pw      = (__bf16*)(ws + 3 * nb + 1024 + (size_t)e * 12);  // 64 KB packed (W1|W2)
    __bf16* z1      = (__bf16*)(ws + 3 * nb + 1024 + (size_t)e * 12 + 65536);
    __bf16* h1      = z1 + (size_t)n * D;
    __bf16* z2      = h1 + (size_t)n * D;

    int nzb = (n + 1023) / 1024;               // counts-zero blocks
    int e4b = ((e + 3) / 4 + 255) / 256;       // 4x edge-parallel blocks
    int sb  = (n + 2047) / 2048;               // scan blocks (<= 64)
    int gb  = (n + 63) / 64;                   // gemm blocks
    int ab  = ((n * 16) + 255) / 256;          // agg blocks

    prep_kernel<<<128 + nzb, 256, 0, stream>>>(W1, W2, pw, counts, n);
    // gemm1 + count co-scheduled (independent work, MFMA hides atomic latency)
    mega1_kernel<<<gb + e4b, 256, 0, stream>>>(x, pw, z1, n, gb, dst, counts, eoff, e);
    scan_part<<<sb, 256, 0, stream>>>(counts, partial, n);
    scan_top<<<1, 256, 0, stream>>>(partial, sb);
    scan_down<<<sb, 256, 0, stream>>>(counts, partial, rowptr, dinv, n);
    fill_kernel<<<e4b, 256, 0, stream>>>(src, dst, rowptr, eoff, dinv, csr, e);

    agg1_kernel<<<ab, 256, 0, stream>>>(z1, rowptr, counts, csr, dinv, b1, h1, n);
    gemm2_mfma<<<gb, 256, 0, stream>>>(h1, pw + 16384, z2, n);
    agg2_fc_kernel<<<ab, 256, 0, stream>>>(z2, rowptr, counts, csr, dinv, b2, Wfc, bfc, out, n);
}